// Round 2
// baseline (2635.556 us; speedup 1.0000x reference)
//
#include <hip/hip_runtime.h>
#include <hip/hip_bf16.h>
#include <cstdint>

#define N_NODES 100000
#define N_EDGES 1600000
#define DD 128

// coarse buckets: 512 nodes each
#define NC 196
#define CSHIFT 9
#define CMASK 511
// fine buckets: 64 nodes each, 8 per coarse
#define NFINE 1568
#define EPB 8192       // edges per partition block
#define NPB 196        // partition blocks
#define FCAP 9216      // max edges per coarse bucket staged in LDS (lambda=8192)

typedef float f32x4 __attribute__((ext_vector_type(4)));
typedef __bf16 bf16x8 __attribute__((ext_vector_type(8)));

union ABFrag { uint4 u4; uint16_t us[8]; bf16x8 v; };

__device__ __forceinline__ float bf2f(uint16_t u) {
  return __uint_as_float(((uint32_t)u) << 16);
}
__device__ __forceinline__ uint16_t f2bf(float f) {
  uint32_t u = __float_as_uint(f);
  uint32_t r = (u + 0x7fffu + ((u >> 16) & 1u)) >> 16;
  return (uint16_t)r;
}

// ---------------- coarse histogram (LDS-staged) ----------------
__global__ __launch_bounds__(256) void hist_coarse_k(const int* __restrict__ dst,
                                                     int* __restrict__ ch) {
  __shared__ int lh[NC];
  if (threadIdx.x < NC) lh[threadIdx.x] = 0;
  __syncthreads();
  int stride = gridDim.x * blockDim.x;
  for (int e = blockIdx.x * blockDim.x + threadIdx.x; e < N_EDGES; e += stride)
    atomicAdd(&lh[dst[e] >> CSHIFT], 1);
  __syncthreads();
  if (threadIdx.x < NC) atomicAdd(&ch[threadIdx.x], lh[threadIdx.x]);
}

// ---------------- tiny scan over 196 coarse counts ----------------
__global__ __launch_bounds__(256) void scan_coarse_k(const int* __restrict__ ch,
                                                     int* __restrict__ coff,
                                                     int* __restrict__ gcursor) {
  __shared__ int s[NC];
  if (threadIdx.x < NC) s[threadIdx.x] = ch[threadIdx.x];
  __syncthreads();
  if (threadIdx.x == 0) {
    int run = 0;
    for (int i = 0; i < NC; ++i) { coff[i] = run; gcursor[i] = run; run += s[i]; }
    coff[NC] = run;
  }
}

// ---------------- partition edges into coarse buckets (LDS staged flush) --------
__global__ __launch_bounds__(256) void partition_k(const int* __restrict__ src,
                                                   const int* __restrict__ dst,
                                                   int* __restrict__ gcursor,
                                                   uint32_t* __restrict__ ec) {
  __shared__ int lhist[NC];
  __shared__ int lscan[NC + 1];
  __shared__ int lcur[NC];
  __shared__ int gbase[NC];
  __shared__ uint32_t staged[EPB];
  const int tid = threadIdx.x;
  const int b0 = blockIdx.x * EPB;
  const int cnt = min(EPB, N_EDGES - b0);
  if (tid < NC) lhist[tid] = 0;
  __syncthreads();
  for (int i = tid; i < cnt; i += 256)
    atomicAdd(&lhist[dst[b0 + i] >> CSHIFT], 1);
  __syncthreads();
  if (tid == 0) {
    int run = 0;
    for (int c = 0; c < NC; ++c) { lscan[c] = run; run += lhist[c]; }
    lscan[NC] = run;
  }
  __syncthreads();
  if (tid < NC) {
    lcur[tid] = lscan[tid];
    gbase[tid] = atomicAdd(&gcursor[tid], lhist[tid]);
  }
  __syncthreads();
  for (int i = tid; i < cnt; i += 256) {
    int d = dst[b0 + i];
    int c = d >> CSHIFT;
    int p = atomicAdd(&lcur[c], 1);
    staged[p] = ((uint32_t)src[b0 + i] << CSHIFT) | (uint32_t)(d & CMASK);
  }
  __syncthreads();
  for (int i = tid; i < cnt; i += 256) {
    int lo = 0, hi = NC - 1;
    while (lo < hi) {
      int mid = (lo + hi + 1) >> 1;
      if (lscan[mid] <= i) lo = mid; else hi = mid - 1;
    }
    ec[gbase[lo] + (i - lscan[lo])] = staged[i];
  }
}

// ---------------- sort coarse bucket into 8 fine buckets (all in LDS) ----------
__global__ __launch_bounds__(256) void finesort_k(const int* __restrict__ coff,
                                                  const uint32_t* __restrict__ ec,
                                                  uint32_t* __restrict__ ef,
                                                  int* __restrict__ foff) {
  __shared__ int fh[8];
  __shared__ int fscan[9];
  __shared__ int fcur[8];
  __shared__ uint32_t staged[FCAP];
  const int tid = threadIdx.x;
  const int c = blockIdx.x;
  const int base = coff[c];
  const int cnt = coff[c + 1] - base;
  if (tid < 8) fh[tid] = 0;
  __syncthreads();
  for (int i = tid; i < cnt; i += 256)
    atomicAdd(&fh[(ec[base + i] >> 6) & 7], 1);
  __syncthreads();
  if (tid == 0) {
    int run = 0;
    for (int f = 0; f < 8; ++f) { fscan[f] = run; run += fh[f]; }
    fscan[8] = run;
  }
  __syncthreads();
  if (tid < 8) fcur[tid] = fscan[tid];
  if (tid < 9) foff[c * 8 + tid] = base + ((tid < 8) ? 0 : 0); // placeholder, fixed below
  __syncthreads();
  if (tid < 9) foff[c * 8 + tid] = base + fscan[tid];
  for (int i = tid; i < cnt; i += 256) {
    uint32_t u = ec[base + i];
    int f = (u >> 6) & 7;
    int p = atomicAdd(&fcur[f], 1);
    if (p < FCAP) staged[p] = ((u >> CSHIFT) << 6) | (u & 63);
  }
  __syncthreads();
  for (int i = tid; i < cnt; i += 256) ef[base + i] = staged[i];
}

// ---------------- weight fragment prep ----------------
// wfrag layout: [o(4)][s(4)][t(8)][lane(64)][i(8)] bf16, o = {W0,rW0,W1,rW1}
__global__ __launch_bounds__(64) void wprep_k(const float* __restrict__ w0, const float* __restrict__ rw0,
                                              const float* __restrict__ w1, const float* __restrict__ rw1,
                                              uint16_t* __restrict__ wfrag) {
  int b = blockIdx.x;  // o*32 + s*8 + t
  int o = b >> 5, s = (b >> 3) & 3, t = b & 7, l = threadIdx.x;
  const float* W = (o == 0) ? w0 : (o == 1) ? rw0 : (o == 2) ? w1 : rw1;
  #pragma unroll
  for (int i = 0; i < 8; ++i) {
    int k = s * 32 + ((l >> 4) << 3) + i;
    int cc = t * 16 + (l & 15);
    wfrag[((size_t)b * 64 + l) * 8 + i] = f2bf(W[k * DD + cc]);
  }
}

// ---------------- dual GEMM: m = x@W ; r = relu(x@rW + rb) ----------------
template <bool AFFINE>
__global__ __launch_bounds__(256) void gemm_dual(
    const float* __restrict__ xf,        // !AFFINE: fp32 input
    const uint32_t* __restrict__ xb,     // AFFINE: bf16-pair input
    const float2* __restrict__ afin,     // AFFINE: per-col (scale, shift)
    const uint4* __restrict__ wfragL,    // [2][4][8][64] x 16B
    const float* __restrict__ rbias,
    uint16_t* __restrict__ mo, uint16_t* __restrict__ ro) {
  const int w = threadIdx.x >> 6, l = threadIdx.x & 63;
  const int row0 = blockIdx.x * 64 + w * 16;
  const int rload = min(row0 + (l & 15), N_NODES - 1);
  const int kg = (l >> 4) * 8;
  ABFrag a[4];
  #pragma unroll
  for (int s = 0; s < 4; ++s) {
    const int k0 = s * 32 + kg;
    if (!AFFINE) {
      const float4* p = (const float4*)(xf + (size_t)rload * DD + k0);
      float4 x0 = p[0], x1 = p[1];
      a[s].us[0] = f2bf(x0.x); a[s].us[1] = f2bf(x0.y);
      a[s].us[2] = f2bf(x0.z); a[s].us[3] = f2bf(x0.w);
      a[s].us[4] = f2bf(x1.x); a[s].us[5] = f2bf(x1.y);
      a[s].us[6] = f2bf(x1.z); a[s].us[7] = f2bf(x1.w);
    } else {
      uint4 hv = *(const uint4*)(xb + (size_t)rload * 64 + k0 / 2);
      uint32_t hu[4] = {hv.x, hv.y, hv.z, hv.w};
      #pragma unroll
      for (int q = 0; q < 4; ++q) {
        int cc = k0 + 2 * q;
        float2 A0 = afin[cc], A1 = afin[cc + 1];
        float f0 = bf2f((uint16_t)hu[q]) * A0.x + A0.y;
        float f1 = bf2f((uint16_t)(hu[q] >> 16)) * A1.x + A1.y;
        a[s].us[2 * q] = f2bf(f0);
        a[s].us[2 * q + 1] = f2bf(f1);
      }
    }
  }
  const int colb = l & 15;
  const int rbase = row0 + (l >> 4) * 4;
  #pragma unroll
  for (int oo = 0; oo < 2; ++oo) {
    #pragma unroll
    for (int t = 0; t < 8; ++t) {
      f32x4 acc = {0.f, 0.f, 0.f, 0.f};
      #pragma unroll
      for (int s = 0; s < 4; ++s) {
        ABFrag bfr;
        bfr.u4 = wfragL[((oo * 4 + s) * 8 + t) * 64 + l];
        acc = __builtin_amdgcn_mfma_f32_16x16x32_bf16(a[s].v, bfr.v, acc, 0, 0, 0);
      }
      const int col = t * 16 + colb;
      if (oo == 0) {
        #pragma unroll
        for (int rr = 0; rr < 4; ++rr) {
          int rowo = rbase + rr;
          if (rowo < N_NODES) mo[(size_t)rowo * DD + col] = f2bf(acc[rr]);
        }
      } else {
        float rbv = rbias[col];
        #pragma unroll
        for (int rr = 0; rr < 4; ++rr) {
          int rowo = rbase + rr;
          if (rowo < N_NODES) ro[(size_t)rowo * DD + col] = f2bf(fmaxf(acc[rr] + rbv, 0.f));
        }
      }
    }
  }
}

// ---------------- per-fine-bucket aggregate + bias + relu + residual + BN stats
__global__ __launch_bounds__(256) void agg_fine_k(
    const int* __restrict__ foff, const uint32_t* __restrict__ ef,
    const uint32_t* __restrict__ m2, const uint32_t* __restrict__ r2,
    const float* __restrict__ bias, uint32_t* __restrict__ h2,
    float* __restrict__ stats) {
  __shared__ float acc[64][128];   // 32 KB
  __shared__ float red[4][128];
  const int tid = threadIdx.x;
  const int w = tid >> 6, l = tid & 63;
  const int fb = blockIdx.x;
  const int nb0 = fb * 64;
  const int e0 = foff[fb], e1 = foff[fb + 1];
  // zero accumulator
  {
    float4* af4 = (float4*)(&acc[0][0]);
    #pragma unroll
    for (int k = 0; k < 8; ++k) af4[tid + k * 256] = make_float4(0.f, 0.f, 0.f, 0.f);
  }
  __syncthreads();
  // edge accumulation: wave w takes edges e0+w, e0+w+4, ...
  int i = e0 + w;
  for (; i + 8 <= e1; i += 8) {
    uint32_t ua = ef[i], ub = ef[i + 4];
    int sa = ua >> 6, da = ua & 63;
    int sb = ub >> 6, db = ub & 63;
    uint32_t va = m2[(size_t)sa * 64 + l];
    uint32_t vb = m2[(size_t)sb * 64 + l];
    atomicAdd(&acc[da][2 * l], bf2f((uint16_t)va));
    atomicAdd(&acc[da][2 * l + 1], bf2f((uint16_t)(va >> 16)));
    atomicAdd(&acc[db][2 * l], bf2f((uint16_t)vb));
    atomicAdd(&acc[db][2 * l + 1], bf2f((uint16_t)(vb >> 16)));
  }
  for (; i < e1; i += 4) {
    uint32_t u = ef[i];
    int s = u >> 6, d = u & 63;
    uint32_t v = m2[(size_t)s * 64 + l];
    atomicAdd(&acc[d][2 * l], bf2f((uint16_t)v));
    atomicAdd(&acc[d][2 * l + 1], bf2f((uint16_t)(v >> 16)));
  }
  __syncthreads();
  // epilogue: bias, relu, residual, bn stats
  const float bb0 = bias[2 * l], bb1 = bias[2 * l + 1];
  float ls0 = 0.f, lsq0 = 0.f, ls1 = 0.f, lsq1 = 0.f;
  #pragma unroll
  for (int k = 0; k < 16; ++k) {
    int n = (k << 2) + w;
    int ng = nb0 + n;
    if (ng < N_NODES) {
      float a0 = fmaxf(acc[n][2 * l] + bb0, 0.f);
      float a1 = fmaxf(acc[n][2 * l + 1] + bb1, 0.f);
      uint32_t rv = r2[(size_t)ng * 64 + l];
      float h0 = a0 + bf2f((uint16_t)rv);
      float h1 = a1 + bf2f((uint16_t)(rv >> 16));
      h2[(size_t)ng * 64 + l] = (uint32_t)f2bf(h0) | ((uint32_t)f2bf(h1) << 16);
      ls0 += h0; lsq0 += h0 * h0;
      ls1 += h1; lsq1 += h1 * h1;
    }
  }
  red[w][2 * l] = ls0; red[w][2 * l + 1] = ls1;
  __syncthreads();
  if (tid < 128) {
    float s = red[0][tid] + red[1][tid] + red[2][tid] + red[3][tid];
    atomicAdd(&stats[tid], s);
  }
  __syncthreads();
  red[w][2 * l] = lsq0; red[w][2 * l + 1] = lsq1;
  __syncthreads();
  if (tid < 128) {
    float s = red[0][tid] + red[1][tid] + red[2][tid] + red[3][tid];
    atomicAdd(&stats[128 + tid], s);
  }
}

// ---------------- BN affine precompute ----------------
__global__ void affine_k(const float* __restrict__ stats, const float* __restrict__ g,
                         const float* __restrict__ beta, float2* __restrict__ af) {
  int c = threadIdx.x;
  float mu = stats[c] / (float)N_NODES;
  float var = stats[128 + c] / (float)N_NODES - mu * mu;
  float sc = g[c] * rsqrtf(var + 1e-5f);
  af[c] = make_float2(sc, beta[c] - mu * sc);
}

// ---------------- final BN apply ----------------
__global__ __launch_bounds__(256) void bn_out(const uint32_t* __restrict__ h2,
                                              const float2* __restrict__ af1,
                                              float* __restrict__ out) {
  int stride = gridDim.x * blockDim.x;
  for (int i = blockIdx.x * blockDim.x + threadIdx.x; i < N_NODES * 64; i += stride) {
    uint32_t u = h2[i];
    int c0 = (i & 63) * 2;
    float2 A = af1[c0], B = af1[c0 + 1];
    float2 o;
    o.x = bf2f((uint16_t)u) * A.x + A.y;
    o.y = bf2f((uint16_t)(u >> 16)) * B.x + B.y;
    *(float2*)(out + (size_t)i * 2) = o;
  }
}

extern "C" void kernel_launch(void* const* d_in, const int* in_sizes, int n_in,
                              void* d_out, int out_size, void* d_ws, size_t ws_size,
                              hipStream_t stream) {
  const float* feats = (const float*)d_in[0];
  const int* srcI = (const int*)d_in[1];
  const int* dstI = (const int*)d_in[2];
  const float* W0 = (const float*)d_in[3];
  const float* b0 = (const float*)d_in[4];
  const float* rW0 = (const float*)d_in[5];
  const float* rb0 = (const float*)d_in[6];
  const float* g0 = (const float*)d_in[7];
  const float* be0 = (const float*)d_in[8];
  const float* W1 = (const float*)d_in[9];
  const float* b1 = (const float*)d_in[10];
  const float* rW1 = (const float*)d_in[11];
  const float* rb1 = (const float*)d_in[12];
  const float* g1 = (const float*)d_in[13];
  const float* be1 = (const float*)d_in[14];
  float* out = (float*)d_out;

  char* ws = (char*)d_ws;
  size_t off = 0;
  auto alloc = [&](size_t bytes) {
    size_t r = off;
    off += (bytes + 255) & ~(size_t)255;
    return r;
  };
  uint16_t* wfrag = (uint16_t*)(ws + alloc(65536 * 2));
  float* stats = (float*)(ws + alloc(512 * 4));
  float2* af = (float2*)(ws + alloc(256 * 8));
  int* ch = (int*)(ws + alloc(NC * 4));
  int* coff = (int*)(ws + alloc((NC + 1) * 4));
  int* gcursor = (int*)(ws + alloc(NC * 4));
  int* foff = (int*)(ws + alloc((NFINE + 1) * 4));
  uint32_t* ec = (uint32_t*)(ws + alloc((size_t)N_EDGES * 4));
  uint32_t* ef = (uint32_t*)(ws + alloc((size_t)N_EDGES * 4));
  uint16_t* mb = (uint16_t*)(ws + alloc((size_t)N_NODES * DD * 2));
  uint16_t* rbuf = (uint16_t*)(ws + alloc((size_t)N_NODES * DD * 2));
  uint16_t* hb = (uint16_t*)(ws + alloc((size_t)N_NODES * DD * 2));

  hipMemsetAsync(ch, 0, NC * 4, stream);
  hipMemsetAsync(stats, 0, 512 * 4, stream);

  hist_coarse_k<<<392, 256, 0, stream>>>(dstI, ch);
  scan_coarse_k<<<1, 256, 0, stream>>>(ch, coff, gcursor);
  partition_k<<<NPB, 256, 0, stream>>>(srcI, dstI, gcursor, ec);
  finesort_k<<<NC, 256, 0, stream>>>(coff, ec, ef, foff);
  wprep_k<<<128, 64, 0, stream>>>(W0, rW0, W1, rW1, wfrag);

  const int gemm_grid = (N_NODES + 63) / 64;
  gemm_dual<false><<<gemm_grid, 256, 0, stream>>>(feats, nullptr, nullptr, (const uint4*)wfrag,
                                                  rb0, mb, rbuf);
  agg_fine_k<<<NFINE, 256, 0, stream>>>(foff, ef, (const uint32_t*)mb, (const uint32_t*)rbuf,
                                        b0, (uint32_t*)hb, stats);
  affine_k<<<1, 128, 0, stream>>>(stats, g0, be0, af);
  gemm_dual<true><<<gemm_grid, 256, 0, stream>>>(nullptr, (const uint32_t*)hb, af,
                                                 (const uint4*)(wfrag + 32768), rb1, mb, rbuf);
  agg_fine_k<<<NFINE, 256, 0, stream>>>(foff, ef, (const uint32_t*)mb, (const uint32_t*)rbuf,
                                        b1, (uint32_t*)hb, stats + 256);
  affine_k<<<1, 128, 0, stream>>>(stats + 256, g1, be1, af + 128);
  bn_out<<<2048, 256, 0, stream>>>((const uint32_t*)hb, af + 128, out);
}

// Round 4
// 509.480 us; speedup vs baseline: 5.1730x; 5.1730x over previous
//
#include <hip/hip_runtime.h>
#include <hip/hip_bf16.h>
#include <cstdint>

#define N_NODES 100000
#define N_EDGES 1600000
#define DD 128

// coarse buckets: 512 nodes each
#define NC 196
#define CSHIFT 9
#define CMASK 511
#define EPB 8192       // edges per partition block
#define NPB 196        // partition blocks
#define FCAP 9216      // max edges per coarse bucket (mean 8192, +11 sigma)

typedef float f32x4 __attribute__((ext_vector_type(4)));
typedef __bf16 bf16x8 __attribute__((ext_vector_type(8)));

union ABFrag { uint4 u4; uint16_t us[8]; bf16x8 v; };

__device__ __forceinline__ float bf2f(uint16_t u) {
  return __uint_as_float(((uint32_t)u) << 16);
}
__device__ __forceinline__ uint16_t f2bf(float f) {
  uint32_t u = __float_as_uint(f);
  uint32_t r = (u + 0x7fffu + ((u >> 16) & 1u)) >> 16;
  return (uint16_t)r;
}

// ---------------- coarse histogram (LDS-staged) ----------------
__global__ __launch_bounds__(256) void hist_coarse_k(const int* __restrict__ dst,
                                                     int* __restrict__ ch) {
  __shared__ int lh[NC];
  if (threadIdx.x < NC) lh[threadIdx.x] = 0;
  __syncthreads();
  int stride = gridDim.x * blockDim.x;
  for (int e = blockIdx.x * blockDim.x + threadIdx.x; e < N_EDGES; e += stride)
    atomicAdd(&lh[dst[e] >> CSHIFT], 1);
  __syncthreads();
  if (threadIdx.x < NC) atomicAdd(&ch[threadIdx.x], lh[threadIdx.x]);
}

// ---------------- tiny scan over 196 coarse counts ----------------
__global__ __launch_bounds__(256) void scan_coarse_k(const int* __restrict__ ch,
                                                     int* __restrict__ coff,
                                                     int* __restrict__ gcursor) {
  __shared__ int s[NC];
  if (threadIdx.x < NC) s[threadIdx.x] = ch[threadIdx.x];
  __syncthreads();
  if (threadIdx.x == 0) {
    int run = 0;
    for (int i = 0; i < NC; ++i) { coff[i] = run; gcursor[i] = run; run += s[i]; }
    coff[NC] = run;
  }
}

// ---------------- partition edges into coarse buckets (LDS staged flush) --------
__global__ __launch_bounds__(256) void partition_k(const int* __restrict__ src,
                                                   const int* __restrict__ dst,
                                                   int* __restrict__ gcursor,
                                                   uint32_t* __restrict__ ec) {
  __shared__ int lhist[NC];
  __shared__ int lscan[NC + 1];
  __shared__ int lcur[NC];
  __shared__ int gbase[NC];
  __shared__ uint32_t staged[EPB];
  const int tid = threadIdx.x;
  const int b0 = blockIdx.x * EPB;
  const int cnt = min(EPB, N_EDGES - b0);
  if (tid < NC) lhist[tid] = 0;
  __syncthreads();
  for (int i = tid; i < cnt; i += 256)
    atomicAdd(&lhist[dst[b0 + i] >> CSHIFT], 1);
  __syncthreads();
  if (tid == 0) {
    int run = 0;
    for (int c = 0; c < NC; ++c) { lscan[c] = run; run += lhist[c]; }
    lscan[NC] = run;
  }
  __syncthreads();
  if (tid < NC) {
    lcur[tid] = lscan[tid];
    gbase[tid] = atomicAdd(&gcursor[tid], lhist[tid]);
  }
  __syncthreads();
  for (int i = tid; i < cnt; i += 256) {
    int d = dst[b0 + i];
    int c = d >> CSHIFT;
    int p = atomicAdd(&lcur[c], 1);
    staged[p] = ((uint32_t)src[b0 + i] << CSHIFT) | (uint32_t)(d & CMASK);
  }
  __syncthreads();
  for (int i = tid; i < cnt; i += 256) {
    int lo = 0, hi = NC - 1;
    while (lo < hi) {
      int mid = (lo + hi + 1) >> 1;
      if (lscan[mid] <= i) lo = mid; else hi = mid - 1;
    }
    ec[gbase[lo] + (i - lscan[lo])] = staged[i];
  }
}

// ------- 512-way counting sort per coarse bucket -> dst-sorted edges + row_ptr
__global__ __launch_bounds__(256) void finesort_k(const int* __restrict__ coff,
                                                  const uint32_t* __restrict__ ec,
                                                  uint32_t* __restrict__ ef,
                                                  int* __restrict__ row_ptr) {
  __shared__ int h[512];
  __shared__ int sc[513];
  __shared__ int cur[512];
  __shared__ int wsum[4];
  __shared__ uint32_t staged[FCAP];
  const int tid = threadIdx.x;
  const int c = blockIdx.x;
  const int base = coff[c];
  const int cnt = coff[c + 1] - base;
  h[tid] = 0; h[tid + 256] = 0;
  __syncthreads();
  for (int i = tid; i < cnt; i += 256)
    atomicAdd(&h[ec[base + i] & CMASK], 1);
  __syncthreads();
  // exclusive scan of h[512]: thread t owns elems {2t, 2t+1}; wave w covers 128 elems
  {
    int a = h[2 * tid], b = h[2 * tid + 1];
    int s = a + b;
    int ln = tid & 63, w = tid >> 6;
    int incl = s;
    #pragma unroll
    for (int o = 1; o < 64; o <<= 1) {
      int t2 = __shfl_up(incl, o);
      if (ln >= o) incl += t2;
    }
    if (ln == 63) wsum[w] = incl;
    __syncthreads();
    int woff = 0;
    #pragma unroll
    for (int i = 0; i < 4; ++i) if (i < w) woff += wsum[i];
    int exc = woff + incl - s;
    sc[2 * tid] = exc;
    sc[2 * tid + 1] = exc + a;
    if (tid == 255) sc[512] = woff + incl;
  }
  __syncthreads();
  cur[tid] = sc[tid]; cur[tid + 256] = sc[tid + 256];
  __syncthreads();
  for (int i = tid; i < cnt; i += 256) {
    uint32_t u = ec[base + i];
    int p = atomicAdd(&cur[u & CMASK], 1);
    if (p < FCAP) staged[p] = u >> CSHIFT;   // payload = src id
  }
  __syncthreads();
  for (int i = tid; i < cnt; i += 256) ef[base + i] = staged[i];
  for (int n = tid; n < 512; n += 256) {
    int v = c * 512 + n;
    if (v < N_NODES) row_ptr[v] = base + sc[n];
  }
  if (c == 0 && tid == 0) row_ptr[N_NODES] = N_EDGES;
}

// ---------------- weight fragment prep ----------------
// wfrag layout: [o(4)][s(4)][t(8)][lane(64)][i(8)] bf16, o = {W0,rW0,W1,rW1}
__global__ __launch_bounds__(64) void wprep_k(const float* __restrict__ w0, const float* __restrict__ rw0,
                                              const float* __restrict__ w1, const float* __restrict__ rw1,
                                              uint16_t* __restrict__ wfrag) {
  int b = blockIdx.x;  // o*32 + s*8 + t
  int o = b >> 5, s = (b >> 3) & 3, t = b & 7, l = threadIdx.x;
  const float* W = (o == 0) ? w0 : (o == 1) ? rw0 : (o == 2) ? w1 : rw1;
  #pragma unroll
  for (int i = 0; i < 8; ++i) {
    int k = s * 32 + ((l >> 4) << 3) + i;
    int cc = t * 16 + (l & 15);
    wfrag[((size_t)b * 64 + l) * 8 + i] = f2bf(W[k * DD + cc]);
  }
}

// ---------------- dual GEMM: m = x@W ; r = relu(x@rW + rb) ----------------
template <bool AFFINE>
__global__ __launch_bounds__(256) void gemm_dual(
    const float* __restrict__ xf,        // !AFFINE: fp32 input
    const uint32_t* __restrict__ xb,     // AFFINE: bf16-pair input
    const float2* __restrict__ afin,     // AFFINE: per-col (scale, shift)
    const uint4* __restrict__ wfragL,    // [2][4][8][64] x 16B
    const float* __restrict__ rbias,
    uint16_t* __restrict__ mo, uint16_t* __restrict__ ro) {
  const int w = threadIdx.x >> 6, l = threadIdx.x & 63;
  const int row0 = blockIdx.x * 64 + w * 16;
  const int rload = min(row0 + (l & 15), N_NODES - 1);
  const int kg = (l >> 4) * 8;
  ABFrag a[4];
  #pragma unroll
  for (int s = 0; s < 4; ++s) {
    const int k0 = s * 32 + kg;
    if (!AFFINE) {
      const float4* p = (const float4*)(xf + (size_t)rload * DD + k0);
      float4 x0 = p[0], x1 = p[1];
      a[s].us[0] = f2bf(x0.x); a[s].us[1] = f2bf(x0.y);
      a[s].us[2] = f2bf(x0.z); a[s].us[3] = f2bf(x0.w);
      a[s].us[4] = f2bf(x1.x); a[s].us[5] = f2bf(x1.y);
      a[s].us[6] = f2bf(x1.z); a[s].us[7] = f2bf(x1.w);
    } else {
      uint4 hv = *(const uint4*)(xb + (size_t)rload * 64 + k0 / 2);
      uint32_t hu[4] = {hv.x, hv.y, hv.z, hv.w};
      #pragma unroll
      for (int q = 0; q < 4; ++q) {
        int cc = k0 + 2 * q;
        float2 A0 = afin[cc], A1 = afin[cc + 1];
        float f0 = bf2f((uint16_t)hu[q]) * A0.x + A0.y;
        float f1 = bf2f((uint16_t)(hu[q] >> 16)) * A1.x + A1.y;
        a[s].us[2 * q] = f2bf(f0);
        a[s].us[2 * q + 1] = f2bf(f1);
      }
    }
  }
  const int colb = l & 15;
  const int rbase = row0 + (l >> 4) * 4;
  #pragma unroll
  for (int oo = 0; oo < 2; ++oo) {
    #pragma unroll
    for (int t = 0; t < 8; ++t) {
      f32x4 acc = {0.f, 0.f, 0.f, 0.f};
      #pragma unroll
      for (int s = 0; s < 4; ++s) {
        ABFrag bfr;
        bfr.u4 = wfragL[((oo * 4 + s) * 8 + t) * 64 + l];
        acc = __builtin_amdgcn_mfma_f32_16x16x32_bf16(a[s].v, bfr.v, acc, 0, 0, 0);
      }
      const int col = t * 16 + colb;
      if (oo == 0) {
        #pragma unroll
        for (int rr = 0; rr < 4; ++rr) {
          int rowo = rbase + rr;
          if (rowo < N_NODES) mo[(size_t)rowo * DD + col] = f2bf(acc[rr]);
        }
      } else {
        float rbv = rbias[col];
        #pragma unroll
        for (int rr = 0; rr < 4; ++rr) {
          int rowo = rbase + rr;
          if (rowo < N_NODES) ro[(size_t)rowo * DD + col] = f2bf(fmaxf(acc[rr] + rbv, 0.f));
        }
      }
    }
  }
}

// ------- wave-per-node aggregate + bias + relu + residual + BN stats (unroll 8)
__global__ __launch_bounds__(256) void agg_node_k(
    const int* __restrict__ row_ptr, const uint32_t* __restrict__ ef,
    const uint32_t* __restrict__ m2, const uint32_t* __restrict__ r2,
    const float* __restrict__ bias, uint32_t* __restrict__ h2,
    float* __restrict__ stats) {
  const int w = threadIdx.x >> 6, l = threadIdx.x & 63;
  const int gw = blockIdx.x * 4 + w;
  const int nw = gridDim.x * 4;
  const float bb0 = bias[2 * l], bb1 = bias[2 * l + 1];
  float ls0 = 0.f, lsq0 = 0.f, ls1 = 0.f, lsq1 = 0.f;
  for (int v = gw; v < N_NODES; v += nw) {
    const int j0 = row_ptr[v], j1 = row_ptr[v + 1];
    float a0 = 0.f, a1 = 0.f;
    int j = j0;
    for (; j + 8 <= j1; j += 8) {
      int s0 = ef[j], s1 = ef[j + 1], s2 = ef[j + 2], s3 = ef[j + 3];
      int s4 = ef[j + 4], s5 = ef[j + 5], s6 = ef[j + 6], s7 = ef[j + 7];
      uint32_t u0 = m2[(size_t)s0 * 64 + l];
      uint32_t u1 = m2[(size_t)s1 * 64 + l];
      uint32_t u2 = m2[(size_t)s2 * 64 + l];
      uint32_t u3 = m2[(size_t)s3 * 64 + l];
      uint32_t u4 = m2[(size_t)s4 * 64 + l];
      uint32_t u5 = m2[(size_t)s5 * 64 + l];
      uint32_t u6 = m2[(size_t)s6 * 64 + l];
      uint32_t u7 = m2[(size_t)s7 * 64 + l];
      a0 += bf2f((uint16_t)u0) + bf2f((uint16_t)u1) + bf2f((uint16_t)u2) + bf2f((uint16_t)u3)
          + bf2f((uint16_t)u4) + bf2f((uint16_t)u5) + bf2f((uint16_t)u6) + bf2f((uint16_t)u7);
      a1 += bf2f((uint16_t)(u0 >> 16)) + bf2f((uint16_t)(u1 >> 16)) + bf2f((uint16_t)(u2 >> 16))
          + bf2f((uint16_t)(u3 >> 16)) + bf2f((uint16_t)(u4 >> 16)) + bf2f((uint16_t)(u5 >> 16))
          + bf2f((uint16_t)(u6 >> 16)) + bf2f((uint16_t)(u7 >> 16));
    }
    for (; j < j1; ++j) {
      uint32_t u = m2[(size_t)((uint32_t)ef[j]) * 64 + l];
      a0 += bf2f((uint16_t)u);
      a1 += bf2f((uint16_t)(u >> 16));
    }
    uint32_t rv = r2[(size_t)v * 64 + l];
    float h0v = fmaxf(a0 + bb0, 0.f) + bf2f((uint16_t)rv);
    float h1v = fmaxf(a1 + bb1, 0.f) + bf2f((uint16_t)(rv >> 16));
    h2[(size_t)v * 64 + l] = (uint32_t)f2bf(h0v) | ((uint32_t)f2bf(h1v) << 16);
    ls0 += h0v; lsq0 += h0v * h0v;
    ls1 += h1v; lsq1 += h1v * h1v;
  }
  __shared__ float red[4][128];
  red[w][2 * l] = ls0; red[w][2 * l + 1] = ls1;
  __syncthreads();
  if (threadIdx.x < 128) {
    float s = red[0][threadIdx.x] + red[1][threadIdx.x] + red[2][threadIdx.x] + red[3][threadIdx.x];
    atomicAdd(&stats[threadIdx.x], s);
  }
  __syncthreads();
  red[w][2 * l] = lsq0; red[w][2 * l + 1] = lsq1;
  __syncthreads();
  if (threadIdx.x < 128) {
    float s = red[0][threadIdx.x] + red[1][threadIdx.x] + red[2][threadIdx.x] + red[3][threadIdx.x];
    atomicAdd(&stats[128 + threadIdx.x], s);
  }
}

// ---------------- BN affine precompute ----------------
__global__ void affine_k(const float* __restrict__ stats, const float* __restrict__ g,
                         const float* __restrict__ beta, float2* __restrict__ af) {
  int c = threadIdx.x;
  float mu = stats[c] / (float)N_NODES;
  float var = stats[128 + c] / (float)N_NODES - mu * mu;
  float sc = g[c] * rsqrtf(var + 1e-5f);
  af[c] = make_float2(sc, beta[c] - mu * sc);
}

// ---------------- final BN apply (vectorized) ----------------
__global__ __launch_bounds__(256) void bn_out(const uint2* __restrict__ h4,
                                              const float2* __restrict__ af1,
                                              float4* __restrict__ out4) {
  int stride = gridDim.x * blockDim.x;
  for (int i = blockIdx.x * blockDim.x + threadIdx.x; i < N_NODES * 32; i += stride) {
    uint2 u = h4[i];
    int c0 = (i & 31) * 4;
    float2 A0 = af1[c0], A1 = af1[c0 + 1], A2 = af1[c0 + 2], A3 = af1[c0 + 3];
    float4 o;
    o.x = bf2f((uint16_t)u.x) * A0.x + A0.y;
    o.y = bf2f((uint16_t)(u.x >> 16)) * A1.x + A1.y;
    o.z = bf2f((uint16_t)u.y) * A2.x + A2.y;
    o.w = bf2f((uint16_t)(u.y >> 16)) * A3.x + A3.y;
    out4[i] = o;
  }
}

extern "C" void kernel_launch(void* const* d_in, const int* in_sizes, int n_in,
                              void* d_out, int out_size, void* d_ws, size_t ws_size,
                              hipStream_t stream) {
  const float* feats = (const float*)d_in[0];
  const int* srcI = (const int*)d_in[1];
  const int* dstI = (const int*)d_in[2];
  const float* W0 = (const float*)d_in[3];
  const float* b0 = (const float*)d_in[4];
  const float* rW0 = (const float*)d_in[5];
  const float* rb0 = (const float*)d_in[6];
  const float* g0 = (const float*)d_in[7];
  const float* be0 = (const float*)d_in[8];
  const float* W1 = (const float*)d_in[9];
  const float* b1 = (const float*)d_in[10];
  const float* rW1 = (const float*)d_in[11];
  const float* rb1 = (const float*)d_in[12];
  const float* g1 = (const float*)d_in[13];
  const float* be1 = (const float*)d_in[14];
  float* out = (float*)d_out;

  char* ws = (char*)d_ws;
  size_t off = 0;
  auto alloc = [&](size_t bytes) {
    size_t r = off;
    off += (bytes + 255) & ~(size_t)255;
    return r;
  };
  uint16_t* wfrag = (uint16_t*)(ws + alloc(65536 * 2));
  float* stats = (float*)(ws + alloc(512 * 4));
  float2* af = (float2*)(ws + alloc(256 * 8));
  int* ch = (int*)(ws + alloc(NC * 4));
  int* coff = (int*)(ws + alloc((NC + 1) * 4));
  int* gcursor = (int*)(ws + alloc(NC * 4));
  int* row_ptr = (int*)(ws + alloc((N_NODES + 1) * 4));
  uint32_t* ec = (uint32_t*)(ws + alloc((size_t)N_EDGES * 4));
  uint32_t* ef = (uint32_t*)(ws + alloc((size_t)N_EDGES * 4));
  uint16_t* mb = (uint16_t*)(ws + alloc((size_t)N_NODES * DD * 2));
  uint16_t* rbuf = (uint16_t*)(ws + alloc((size_t)N_NODES * DD * 2));
  uint16_t* hb = (uint16_t*)(ws + alloc((size_t)N_NODES * DD * 2));

  hipMemsetAsync(ch, 0, NC * 4, stream);
  hipMemsetAsync(stats, 0, 512 * 4, stream);

  hist_coarse_k<<<392, 256, 0, stream>>>(dstI, ch);
  scan_coarse_k<<<1, 256, 0, stream>>>(ch, coff, gcursor);
  partition_k<<<NPB, 256, 0, stream>>>(srcI, dstI, gcursor, ec);
  finesort_k<<<NC, 256, 0, stream>>>(coff, ec, ef, row_ptr);
  wprep_k<<<128, 64, 0, stream>>>(W0, rW0, W1, rW1, wfrag);

  const int gemm_grid = (N_NODES + 63) / 64;
  gemm_dual<false><<<gemm_grid, 256, 0, stream>>>(feats, nullptr, nullptr, (const uint4*)wfrag,
                                                  rb0, mb, rbuf);
  agg_node_k<<<2048, 256, 0, stream>>>(row_ptr, ef, (const uint32_t*)mb, (const uint32_t*)rbuf,
                                       b0, (uint32_t*)hb, stats);
  affine_k<<<1, 128, 0, stream>>>(stats, g0, be0, af);
  gemm_dual<true><<<gemm_grid, 256, 0, stream>>>(nullptr, (const uint32_t*)hb, af,
                                                 (const uint4*)(wfrag + 32768), rb1, mb, rbuf);
  agg_node_k<<<2048, 256, 0, stream>>>(row_ptr, ef, (const uint32_t*)mb, (const uint32_t*)rbuf,
                                       b1, (uint32_t*)hb, stats + 256);
  affine_k<<<1, 128, 0, stream>>>(stats + 256, g1, be1, af + 128);
  bn_out<<<2048, 256, 0, stream>>>((const uint2*)hb, af + 128, (float4*)out);
}